// Round 2
// baseline (55.602 us; speedup 1.0000x reference)
//
#include <hip/hip_runtime.h>
#include <stdint.h>

// FlagBagEncoder: out[t,:] = mean over {k : flags[t,k] > 0.5} of W[k,:], zeros if empty.
// T=100000, K=512, D=64, fp32 in/out.
//
// Two-pass design:
//   pass 1: flags (204.8 MB stream) -> 1-bit mask (6.4 MB static). Pure-BW kernel,
//           tiny VGPR (8 waves/SIMD), only flag loads in the vmcnt FIFO.
//   pass 2: mfma_f32_32x32x16_bf16 over the bitmask. Bitmask is register-resident
//           (16 dwords/lane), B fragments prepacked bf16 (L2-resident, depth-3 ring),
//           counts exact via popcount of the same bits. 32-row tiles halve B traffic.
// Rationale: round-1 single kernel lost ~30% to L2-latency waits on B loads sharing
// the vmcnt FIFO with the HBM flag stream.

#define T_ROWS 100000
#define K_FLAGS 512
#define D_DIM 64
#define TILE_R 32
#define N_TILES (T_ROWS / TILE_R)   // 3125, exact

typedef __attribute__((ext_vector_type(4)))  float f32x4;
typedef __attribute__((ext_vector_type(16))) float f32x16;
typedef __attribute__((ext_vector_type(8)))  short bf16x8;

__device__ uint8_t  g_mask[(size_t)T_ROWS * 64];   // 6.4 MB: row-major, byte l = flags[row][l*8..l*8+7], bit j = flag l*8+j
__device__ uint32_t g_bfrag[32 * 2 * 64 * 4];      // 64 KB: [s][nt][lane][4 dwords]

__device__ __forceinline__ uint32_t f32_to_bf16_rne(float f) {
  union { float f; uint32_t u; } v; v.f = f;
  uint32_t u = v.u;
  return (u + 0x7FFFu + ((u >> 16) & 1u)) >> 16;
}

// B fragments for mfma_f32_32x32x16_bf16:
// lane l: col = (l&31) + 32*nt ; k = 16*s + (l>>5)*8 + e ; dword j holds elems (2j,2j+1) lo|hi.
// Same k-mapping is used for the A (mask) fragment, so any within-group k-permutation cancels.
__global__ void prep_b_kernel(const float* __restrict__ W) {
  int tid = blockIdx.x * blockDim.x + threadIdx.x;
  if (tid >= 32 * 2 * 64) return;
  int lane = tid & 63;
  int nt   = (tid >> 6) & 1;
  int s    = tid >> 7;
  int col  = (lane & 31) + 32 * nt;
  int kb   = 16 * s + (lane >> 5) * 8;
  uint32_t r[4];
#pragma unroll
  for (int j = 0; j < 4; ++j) {
    uint32_t lo = f32_to_bf16_rne(W[(size_t)(kb + 2 * j    ) * D_DIM + col]);
    uint32_t hi = f32_to_bf16_rne(W[(size_t)(kb + 2 * j + 1) * D_DIM + col]);
    r[j] = lo | (hi << 16);
  }
  *reinterpret_cast<uint4*>(&g_bfrag[(size_t)tid * 4]) = make_uint4(r[0], r[1], r[2], r[3]);
}

// Pass 1: one row per wave per iteration; lane l handles flags[row][l*8 .. l*8+8).
// Two coalesced float4 loads (wave covers the full 2 KB row), byte ballot, 64 B store.
__global__ __launch_bounds__(256) void mask_kernel(const float* __restrict__ flags) {
  const int lane   = threadIdx.x & 63;
  const int gwave  = (int)((blockIdx.x * blockDim.x + threadIdx.x) >> 6);
  const int nwaves = (int)((gridDim.x * blockDim.x) >> 6);

  int r = gwave;
  if (r >= T_ROWS) return;

  const float* p = flags + (size_t)r * K_FLAGS + lane * 8;
  f32x4 a0 = *reinterpret_cast<const f32x4*>(p);
  f32x4 a1 = *reinterpret_cast<const f32x4*>(p + 4);

  while (true) {
    const int rn = r + nwaves;
    const bool more = rn < T_ROWS;
    f32x4 b0, b1;
    if (more) {  // prefetch next row while current is in flight / being processed
      const float* pn = flags + (size_t)rn * K_FLAGS + lane * 8;
      b0 = *reinterpret_cast<const f32x4*>(pn);
      b1 = *reinterpret_cast<const f32x4*>(pn + 4);
    }
    uint32_t byte = 0;
#pragma unroll
    for (int j = 0; j < 4; ++j) {
      byte |= (a0[j] > 0.5f) ? (1u << j)       : 0u;
      byte |= (a1[j] > 0.5f) ? (1u << (j + 4)) : 0u;
    }
    g_mask[(size_t)r * 64 + lane] = (uint8_t)byte;  // 64 contiguous bytes per wave
    if (!more) break;
    r = rn; a0 = b0; a1 = b1;
  }
}

// Pass 2: one 32-row tile per wave. A fragment built from register-resident bitmask;
// B from prepacked table with a depth-3 register ring (only B loads in the main-loop FIFO).
__global__ __launch_bounds__(256) void bag_kernel(float* __restrict__ out) {
  const int lane = threadIdx.x & 63;
  const int wave = threadIdx.x >> 6;
  const int tile = blockIdx.x * 4 + wave;
  if (tile >= N_TILES) return;

  const int t0 = tile * TILE_R;
  const int r  = lane & 31;   // A row within tile (also the row whose inv this lane owns)
  const int g  = lane >> 5;   // k half-group

  // load my row's 512 mask bits (16 dwords) once
  union { uint4 q[4]; uint32_t d[16]; } bm;
  const uint4* bm4 = reinterpret_cast<const uint4*>(g_mask + (size_t)(t0 + r) * 64);
#pragma unroll
  for (int i = 0; i < 4; ++i) bm.q[i] = bm4[i];

  // exact count from the same bits the MFMA consumes
  int cnt = 0;
#pragma unroll
  for (int i = 0; i < 16; ++i) cnt += __popc(bm.d[i]);
  const float inv = (cnt > 0) ? (1.0f / (float)cnt) : 0.0f;

  const uint4* bb = reinterpret_cast<const uint4*>(g_bfrag) + lane;

  f32x16 acc0, acc1;
#pragma unroll
  for (int i = 0; i < 16; ++i) { acc0[i] = 0.f; acc1[i] = 0.f; }

  uint4 B[3][2];
  B[0][0] = bb[0 * 64]; B[0][1] = bb[1 * 64];
  B[1][0] = bb[2 * 64]; B[1][1] = bb[3 * 64];

#pragma unroll
  for (int s = 0; s < 32; ++s) {
    const int sp = (s + 2 <= 31) ? s + 2 : 31;   // clamp keeps vm-op count constant
    uint4 nb0 = bb[(sp * 2 + 0) * 64];
    uint4 nb1 = bb[(sp * 2 + 1) * 64];

    // 8 mask bits for this step: k = 16s + g*8 + e  ->  dword s>>1, shift 16*(s&1)+8*g
    const uint32_t byte = (bm.d[s >> 1] >> ((s & 1) * 16 + g * 8)) & 0xFFu;
    bf16x8 af;
#pragma unroll
    for (int e = 0; e < 8; ++e) af[e] = ((byte >> e) & 1u) ? (short)0x3F80 : (short)0;

    acc0 = __builtin_amdgcn_mfma_f32_32x32x16_bf16(
        af, *reinterpret_cast<const bf16x8*>(&B[s % 3][0]), acc0, 0, 0, 0);
    acc1 = __builtin_amdgcn_mfma_f32_32x32x16_bf16(
        af, *reinterpret_cast<const bf16x8*>(&B[s % 3][1]), acc1, 0, 0, 0);

    B[(s + 2) % 3][0] = nb0;
    B[(s + 2) % 3][1] = nb1;
  }

  // C/D layout (HW-verified, m74/m101): col = lane&31, row = (reg&3) + 8*(reg>>2) + 4*(lane>>5)
#pragma unroll
  for (int reg = 0; reg < 16; ++reg) {
    const int row = (reg & 3) + 8 * (reg >> 2) + 4 * g;
    const float invr = __shfl(inv, row);            // lane 'row' holds inv for that row
    float* o = out + (size_t)(t0 + row) * D_DIM + (lane & 31);
    o[0]  = acc0[reg] * invr;
    o[32] = acc1[reg] * invr;
  }
}

extern "C" void kernel_launch(void* const* d_in, const int* in_sizes, int n_in,
                              void* d_out, int out_size, void* d_ws, size_t ws_size,
                              hipStream_t stream) {
  const float* flags = (const float*)d_in[0];
  const float* W     = (const float*)d_in[1];
  float* out         = (float*)d_out;

  hipLaunchKernelGGL(prep_b_kernel, dim3(16), dim3(256), 0, stream, W);
  hipLaunchKernelGGL(mask_kernel, dim3(2048), dim3(256), 0, stream, flags);

  const int blocks = (N_TILES + 3) / 4;  // 4 waves/block, one 32-row tile per wave
  hipLaunchKernelGGL(bag_kernel, dim3(blocks), dim3(256), 0, stream, out);
}

// Round 3
// 53.341 us; speedup vs baseline: 1.0424x; 1.0424x over previous
//
#include <hip/hip_runtime.h>
#include <stdint.h>

// FlagBagEncoder: out[t,:] = mean over {k : flags[t,k] > 0.5} of W[k,:], zeros if empty.
// T=100000, K=512, D=64, fp32 in/out.
//
// Fused single-pass, v3: bf16 MFMA (mask exact in bf16), 16-row tiles,
// mfma_f32_16x16x32_bf16, 4 n-tiles, 16 K-steps.
// Key change vs round 1: B fragments live in LDS (staged once per block from a
// prepacked L2-hot global table). LDS reads use lgkmcnt, so the per-wave vmcnt
// FIFO contains ONLY the streaming flag loads (depth-4 ring, 6 outstanding
// dwordx4/lane) -> no L2-latency waits drain the HBM stream. Main loop is
// barrier-free after the one staging __syncthreads.

#define T_ROWS 100000
#define K_FLAGS 512
#define D_DIM 64
#define TILES (T_ROWS / 16)   // 6250, exact

typedef __attribute__((ext_vector_type(4))) float f32x4;
typedef __attribute__((ext_vector_type(8))) short bf16x8;

// 16 k-steps x 4 n-tiles x 64 lanes x 4 dwords = 64 KB of prepacked B fragments.
__device__ uint32_t g_bfrag[16 * 4 * 64 * 4];

__device__ __forceinline__ uint32_t f32_to_bf16_rne(float f) {
  union { float f; uint32_t u; } v; v.f = f;
  uint32_t u = v.u;
  return (u + 0x7FFFu + ((u >> 16) & 1u)) >> 16;
}

// Fragment mapping (identical for A and B, so within-group k-permutation cancels):
// lane l, element e (0..7): k = (l>>4)*8 + 32*s + e ; A row m = l&15 ; B col n = (l&15)+16*nt.
// Packed dword j holds elements (2j, 2j+1) as (lo, hi) bf16.
__global__ void prep_b_kernel(const float* __restrict__ W) {
  int tid = blockIdx.x * blockDim.x + threadIdx.x;
  if (tid >= 16 * 4 * 64) return;
  int lane = tid & 63;
  int nt   = (tid >> 6) & 3;
  int s    = tid >> 8;
  int n    = (lane & 15) + 16 * nt;
  int kb   = (lane >> 4) * 8 + 32 * s;
  uint32_t r[4];
#pragma unroll
  for (int j = 0; j < 4; ++j) {
    uint32_t lo = f32_to_bf16_rne(W[(size_t)(kb + 2 * j    ) * D_DIM + n]);
    uint32_t hi = f32_to_bf16_rne(W[(size_t)(kb + 2 * j + 1) * D_DIM + n]);
    r[j] = lo | (hi << 16);
  }
  *reinterpret_cast<uint4*>(&g_bfrag[(size_t)tid * 4]) = make_uint4(r[0], r[1], r[2], r[3]);
}

__global__ __launch_bounds__(512, 4) void flagbag_kernel(const float* __restrict__ flags,
                                                         float* __restrict__ out) {
  __shared__ uint4 sB[16 * 4 * 64];   // 64 KB, same layout as g_bfrag

  const int tid = threadIdx.x;
  // cooperative staging: 512 threads x 8 x 16B, coalesced, L2-hot source
  {
    const uint4* gb = reinterpret_cast<const uint4*>(g_bfrag);
#pragma unroll
    for (int j = 0; j < 8; ++j) sB[j * 512 + tid] = gb[j * 512 + tid];
  }
  __syncthreads();   // only barrier in the kernel

  const int lane = tid & 63;
  const int wave = tid >> 6;
  const int tile = blockIdx.x * 8 + wave;
  if (tile >= TILES) return;

  const int t0 = tile * 16;
  const int m  = lane & 15;   // A row within tile / output col within n-tile
  const int kq = lane >> 4;   // k quarter-group

  const float* frow = flags + (size_t)(t0 + m) * K_FLAGS + kq * 8;
  const uint4* sbl  = &sB[lane];

  f32x4 acc[4];
#pragma unroll
  for (int nt = 0; nt < 4; ++nt) acc[nt] = (f32x4){0.f, 0.f, 0.f, 0.f};
  int cnt = 0;

  // depth-4 flag ring (slot = step & 3); issue steps 0..2 up front
  f32x4 ra[4], rb[4];
#pragma unroll
  for (int s = 0; s < 3; ++s) {
    ra[s] = *reinterpret_cast<const f32x4*>(frow + 32 * s);
    rb[s] = *reinterpret_cast<const f32x4*>(frow + 32 * s + 4);
  }

  // B double-buffer from LDS
  uint4 bc[4], bn[4];
#pragma unroll
  for (int nt = 0; nt < 4; ++nt) bc[nt] = sbl[nt * 64];

#pragma unroll
  for (int s = 0; s < 16; ++s) {
    if (s + 3 < 16) {   // compile-time under full unroll
      ra[(s + 3) & 3] = *reinterpret_cast<const f32x4*>(frow + 32 * (s + 3));
      rb[(s + 3) & 3] = *reinterpret_cast<const f32x4*>(frow + 32 * (s + 3) + 4);
    }
    if (s + 1 < 16) {
#pragma unroll
      for (int nt = 0; nt < 4; ++nt) bn[nt] = sbl[((s + 1) * 4 + nt) * 64];
    }

    const f32x4 fa = ra[s & 3];
    const f32x4 fb = rb[s & 3];
    bf16x8 af;
#pragma unroll
    for (int j = 0; j < 4; ++j) {
      const bool sa = fa[j] > 0.5f;
      const bool sb = fb[j] > 0.5f;
      af[j]     = sa ? (short)0x3F80 : (short)0;
      af[j + 4] = sb ? (short)0x3F80 : (short)0;
      cnt += sa ? 1 : 0;
      cnt += sb ? 1 : 0;
    }

#pragma unroll
    for (int nt = 0; nt < 4; ++nt)
      acc[nt] = __builtin_amdgcn_mfma_f32_16x16x32_bf16(
          af, *reinterpret_cast<const bf16x8*>(&bc[nt]), acc[nt], 0, 0, 0);

#pragma unroll
    for (int nt = 0; nt < 4; ++nt) bc[nt] = bn[nt];
  }

  // full row count: lanes {m, m+16, m+32, m+48} each hold 128 of the 512 k's
  cnt += __shfl_xor(cnt, 16);
  cnt += __shfl_xor(cnt, 32);
  const float inv = (cnt > 0) ? (1.0f / (float)cnt) : 0.0f;

  // C/D layout (HW-verified): col = lane&15, row = (lane>>4)*4 + reg
#pragma unroll
  for (int r = 0; r < 4; ++r) {
    const int row = kq * 4 + r;
    const float invr = __shfl(inv, row);   // lane 'row' holds count for row 'row'
    float* orow = out + (size_t)(t0 + row) * D_DIM + m;
#pragma unroll
    for (int nt = 0; nt < 4; ++nt)
      orow[16 * nt] = acc[nt][r] * invr;
  }
}

extern "C" void kernel_launch(void* const* d_in, const int* in_sizes, int n_in,
                              void* d_out, int out_size, void* d_ws, size_t ws_size,
                              hipStream_t stream) {
  const float* flags = (const float*)d_in[0];
  const float* W     = (const float*)d_in[1];
  float* out         = (float*)d_out;

  hipLaunchKernelGGL(prep_b_kernel, dim3(16), dim3(256), 0, stream, W);

  const int blocks = (TILES + 7) / 8;   // 8 waves/block, one 16-row tile per wave
  hipLaunchKernelGGL(flagbag_kernel, dim3(blocks), dim3(512), 0, stream, flags, out);
}

// Round 4
// 53.016 us; speedup vs baseline: 1.0488x; 1.0061x over previous
//
#include <hip/hip_runtime.h>
#include <stdint.h>

// FlagBagEncoder: out[t,:] = mean over {k : flags[t,k] > 0.5} of W[k,:], zeros if empty.
// T=100000, K=512, D=64, fp32 in/out.
//
// v4: fused, bf16 MFMA, 16-row tiles, B staged in LDS (as v3). KEY CHANGE: flag
// loads are now full-sector. v1-v3 had lane(m,kq) read 16 B at rowbase+kq*32
// (stride-32 half-sector gathers -> every 64-B sector requested twice, half-used;
// sector-request rate was 2x byte rate ~= the fill kernel's 7 TB/s request ceiling).
// Using the A/B k-mapping freedom, lane(m,kq) now reads rowbase + s*128 + kq*16
// (load A) and +64 (load B): lanes {m,m+16,m+32,m+48} cover one FULL 64-B sector
// per instruction. B prep uses the identical k-map so the permutation cancels.

#define T_ROWS 100000
#define K_FLAGS 512
#define D_DIM 64
#define TILES (T_ROWS / 16)   // 6250, exact

typedef __attribute__((ext_vector_type(4))) float f32x4;
typedef __attribute__((ext_vector_type(8))) short bf16x8;

// 16 k-steps x 4 n-tiles x 64 lanes x 4 dwords = 64 KB of prepacked B fragments.
__device__ uint32_t g_bfrag[16 * 4 * 64 * 4];

__device__ __forceinline__ uint32_t f32_to_bf16_rne(float f) {
  union { float f; uint32_t u; } v; v.f = f;
  uint32_t u = v.u;
  return (u + 0x7FFFu + ((u >> 16) & 1u)) >> 16;
}

// k-mapping (identical for A and B, so the permutation cancels in the dot product):
// lane l: m = l&15 (A row / B col base), kq = l>>4.
// element e of step s: k = 32*s + (e<4 ? kq*4 + e : 16 + kq*4 + (e-4)).
// A gets e0..3 from a float4 at row m, float-offset 32s + 4kq ("load A"),
//        e4..7 from float-offset 32s + 16 + 4kq ("load B").
// Packed B dword j holds elements (2j, 2j+1) as (lo, hi) bf16:
//   k0(j) = 32s + (j>>1)*16 + 4*kq + (j&1)*2 ; k1(j) = k0(j)+1.
__global__ void prep_b_kernel(const float* __restrict__ W) {
  int tid = blockIdx.x * blockDim.x + threadIdx.x;
  if (tid >= 16 * 4 * 64) return;
  int lane = tid & 63;
  int nt   = (tid >> 6) & 3;
  int s    = tid >> 8;
  int n    = (lane & 15) + 16 * nt;
  int kq   = lane >> 4;
  uint32_t r[4];
#pragma unroll
  for (int j = 0; j < 4; ++j) {
    int k0 = 32 * s + (j >> 1) * 16 + 4 * kq + (j & 1) * 2;
    uint32_t lo = f32_to_bf16_rne(W[(size_t)(k0    ) * D_DIM + n]);
    uint32_t hi = f32_to_bf16_rne(W[(size_t)(k0 + 1) * D_DIM + n]);
    r[j] = lo | (hi << 16);
  }
  *reinterpret_cast<uint4*>(&g_bfrag[(size_t)tid * 4]) = make_uint4(r[0], r[1], r[2], r[3]);
}

__global__ __launch_bounds__(512, 4) void flagbag_kernel(const float* __restrict__ flags,
                                                         float* __restrict__ out) {
  __shared__ uint4 sB[16 * 4 * 64];   // 64 KB, same layout as g_bfrag

  const int tid = threadIdx.x;
  // cooperative staging: 512 threads x 8 x 16B, coalesced, L2-hot source
  {
    const uint4* gb = reinterpret_cast<const uint4*>(g_bfrag);
#pragma unroll
    for (int j = 0; j < 8; ++j) sB[j * 512 + tid] = gb[j * 512 + tid];
  }
  __syncthreads();   // only barrier in the kernel

  const int lane = tid & 63;
  const int wave = tid >> 6;
  const int tile = blockIdx.x * 8 + wave;
  if (tile >= TILES) return;

  const int t0 = tile * 16;
  const int m  = lane & 15;   // A row within tile / output col within n-tile
  const int kq = lane >> 4;   // 16-B granule index within each 64-B sector

  // full-sector mapping: load A at 32s + 4kq floats, load B at +16 floats
  const float* frow = flags + (size_t)(t0 + m) * K_FLAGS + kq * 4;
  const uint4* sbl  = &sB[lane];

  f32x4 acc[4];
#pragma unroll
  for (int nt = 0; nt < 4; ++nt) acc[nt] = (f32x4){0.f, 0.f, 0.f, 0.f};
  int cnt = 0;

  // depth-4 flag ring (slot = step & 3); issue steps 0..2 up front
  f32x4 ra[4], rb[4];
#pragma unroll
  for (int s = 0; s < 3; ++s) {
    ra[s] = *reinterpret_cast<const f32x4*>(frow + 32 * s);
    rb[s] = *reinterpret_cast<const f32x4*>(frow + 32 * s + 16);
  }

  // B double-buffer from LDS
  uint4 bc[4], bn[4];
#pragma unroll
  for (int nt = 0; nt < 4; ++nt) bc[nt] = sbl[nt * 64];

#pragma unroll
  for (int s = 0; s < 16; ++s) {
    if (s + 3 < 16) {   // compile-time under full unroll
      ra[(s + 3) & 3] = *reinterpret_cast<const f32x4*>(frow + 32 * (s + 3));
      rb[(s + 3) & 3] = *reinterpret_cast<const f32x4*>(frow + 32 * (s + 3) + 16);
    }
    if (s + 1 < 16) {
#pragma unroll
      for (int nt = 0; nt < 4; ++nt) bn[nt] = sbl[((s + 1) * 4 + nt) * 64];
    }

    const f32x4 fa = ra[s & 3];
    const f32x4 fb = rb[s & 3];
    bf16x8 af;
#pragma unroll
    for (int j = 0; j < 4; ++j) {
      const bool sa = fa[j] > 0.5f;
      const bool sb = fb[j] > 0.5f;
      af[j]     = sa ? (short)0x3F80 : (short)0;
      af[j + 4] = sb ? (short)0x3F80 : (short)0;
      cnt += sa ? 1 : 0;
      cnt += sb ? 1 : 0;
    }

#pragma unroll
    for (int nt = 0; nt < 4; ++nt)
      acc[nt] = __builtin_amdgcn_mfma_f32_16x16x32_bf16(
          af, *reinterpret_cast<const bf16x8*>(&bc[nt]), acc[nt], 0, 0, 0);

#pragma unroll
    for (int nt = 0; nt < 4; ++nt) bc[nt] = bn[nt];
  }

  // full row count: lanes {m, m+16, m+32, m+48} hold disjoint quarters of row m's 512 k's
  cnt += __shfl_xor(cnt, 16);
  cnt += __shfl_xor(cnt, 32);
  const float inv = (cnt > 0) ? (1.0f / (float)cnt) : 0.0f;

  // C/D layout (HW-verified): col = lane&15, row = (lane>>4)*4 + reg
#pragma unroll
  for (int r = 0; r < 4; ++r) {
    const int row = kq * 4 + r;
    const float invr = __shfl(inv, row);   // lane 'row' holds count for row 'row'
    float* orow = out + (size_t)(t0 + row) * D_DIM + m;
#pragma unroll
    for (int nt = 0; nt < 4; ++nt)
      orow[16 * nt] = acc[nt][r] * invr;
  }
}

extern "C" void kernel_launch(void* const* d_in, const int* in_sizes, int n_in,
                              void* d_out, int out_size, void* d_ws, size_t ws_size,
                              hipStream_t stream) {
  const float* flags = (const float*)d_in[0];
  const float* W     = (const float*)d_in[1];
  float* out         = (float*)d_out;

  hipLaunchKernelGGL(prep_b_kernel, dim3(16), dim3(256), 0, stream, W);

  const int blocks = (TILES + 7) / 8;   // 8 waves/block, one 16-row tile per wave
  hipLaunchKernelGGL(flagbag_kernel, dim3(blocks), dim3(512), 0, stream, flags, out);
}

// Round 5
// 52.256 us; speedup vs baseline: 1.0640x; 1.0145x over previous
//
#include <hip/hip_runtime.h>
#include <stdint.h>

// FlagBagEncoder: out[t,:] = mean over {k : flags[t,k] > 0.5} of W[k,:], zeros if empty.
// T=100000, K=512, D=64, fp32 in/out.
//
// v5: single kernel (no prep launch). Theory: v1-v4 were DRAM-activate-limited --
// each wave touched 16 pages at 128 B/visit (16 rows x 2KB stride), ~49 G ACT/s
// needed at 6.3 TB/s over ~2K banks = under tRC. Fix: phase-L reads the tile
// ROW-SEQUENTIALLY (wave = one full 2-KB row per load pair; the 32-KB tile is one
// contiguous burst -> ~1 ACT per page). Bits exchanged row-major->fragment-major
// through a 1-KB/wave bank-swizzled LDS buffer. W is converted to the bf16
// fragment table per-block in-kernel (W is 128 KB, L1/L2-hot).
// k-map (identical for A and B, permutation cancels): k = 128*kq + 8*s + e.

#define T_ROWS 100000
#define K_FLAGS 512
#define D_DIM 64
#define TILES (T_ROWS / 16)   // 6250, exact

typedef __attribute__((ext_vector_type(4))) float f32x4;
typedef __attribute__((ext_vector_type(8))) short bf16x8;

__device__ __forceinline__ uint32_t f32_to_bf16_rne(float f) {
  union { float f; uint32_t u; } v; v.f = f;
  uint32_t u = v.u;
  return (u + 0x7FFFu + ((u >> 16) & 1u)) >> 16;
}

__global__ __launch_bounds__(512, 4) void flagbag_kernel(const float* __restrict__ flags,
                                                         const float* __restrict__ W,
                                                         float* __restrict__ out) {
  // B-fragment table: [s][nt][lane] -> uint4 (8 bf16). 64 KB.
  __shared__ uint4 sB[16 * 4 * 64];
  // per-wave mask exchange: word j*64 + (x ^ 4j) holds rows 4j..4j+3 (one byte each)
  // of phase-lane x's 8-column slice. 1 KB/wave, bank-swizzled.
  __shared__ uint32_t sM[8][256];

  const int tid = threadIdx.x;

  // ---- per-block W -> bf16 fragment table (k = 128*kq + 8*s + e) ----
  {
#pragma unroll
    for (int p = 0; p < 8; ++p) {
      const int E    = tid + p * 512;
      const int s    = E >> 8;
      const int nt   = (E >> 6) & 3;
      const int ln   = E & 63;
      const int n    = (ln & 15) + 16 * nt;
      const int kq   = ln >> 4;
      const int kb   = 128 * kq + 8 * s;
      uint32_t r[4];
#pragma unroll
      for (int j = 0; j < 4; ++j) {
        uint32_t lo = f32_to_bf16_rne(W[(size_t)(kb + 2 * j    ) * D_DIM + n]);
        uint32_t hi = f32_to_bf16_rne(W[(size_t)(kb + 2 * j + 1) * D_DIM + n]);
        r[j] = lo | (hi << 16);
      }
      sB[E] = make_uint4(r[0], r[1], r[2], r[3]);
    }
  }
  __syncthreads();   // only block-wide barrier

  const int lane = tid & 63;
  const int wave = tid >> 6;
  const int tile = blockIdx.x * 8 + wave;
  if (tile >= TILES) return;

  const int t0 = tile * 16;

  // ---- phase L: row-sequential contiguous read of the 32-KB tile ----
  // lane covers floats [8*lane, 8*lane+8) of each row; rows streamed in order,
  // depth-4 ring -> the tile is one sequential 32-KB burst per wave.
  const float* ft = flags + (size_t)t0 * K_FLAGS + lane * 8;

  uint32_t D0 = 0, D1 = 0, D2 = 0, D3 = 0;   // rows 0-3 / 4-7 / 8-11 / 12-15
  f32x4 ra[4], rb[4];
#pragma unroll
  for (int r = 0; r < 3; ++r) {
    ra[r] = *reinterpret_cast<const f32x4*>(ft + r * K_FLAGS);
    rb[r] = *reinterpret_cast<const f32x4*>(ft + r * K_FLAGS + 4);
  }
#pragma unroll
  for (int r = 0; r < 16; ++r) {
    if (r + 3 < 16) {   // compile-time under full unroll
      ra[(r + 3) & 3] = *reinterpret_cast<const f32x4*>(ft + (r + 3) * K_FLAGS);
      rb[(r + 3) & 3] = *reinterpret_cast<const f32x4*>(ft + (r + 3) * K_FLAGS + 4);
    }
    const f32x4 a = ra[r & 3], b = rb[r & 3];
    uint32_t byte = 0;
#pragma unroll
    for (int j = 0; j < 4; ++j) {
      byte |= (a[j] > 0.5f) ? (1u << j)       : 0u;
      byte |= (b[j] > 0.5f) ? (1u << (j + 4)) : 0u;
    }
    const uint32_t sh = byte << ((r & 3) * 8);
    if ((r >> 2) == 0) D0 |= sh;
    else if ((r >> 2) == 1) D1 |= sh;
    else if ((r >> 2) == 2) D2 |= sh;
    else D3 |= sh;
  }

  uint32_t* sMw = sM[wave];
  sMw[0 * 64 + (lane ^ 0)]  = D0;
  sMw[1 * 64 + (lane ^ 4)]  = D1;
  sMw[2 * 64 + (lane ^ 8)]  = D2;
  sMw[3 * 64 + (lane ^ 12)] = D3;
  // wave-internal LDS write->read: compiler inserts the lgkmcnt wait.

  // ---- phase M: MFMA over the exchanged mask ----
  const int m  = lane & 15;   // A row within tile / output col within n-tile
  const int kq = lane >> 4;
  const int mj = m >> 2, mb = m & 3;
  const uint8_t* sMb = reinterpret_cast<const uint8_t*>(sMw);

  // gather my 16 step-bytes: step s -> phase-lane x = 16*kq + s, word mj, byte mb
  uint32_t mbytes[16];
#pragma unroll
  for (int s = 0; s < 16; ++s)
    mbytes[s] = sMb[(size_t)(mj * 64 + ((16 * kq + s) ^ (4 * mj))) * 4 + mb];

  int cnt = 0;
#pragma unroll
  for (int s = 0; s < 16; ++s) cnt += __popc(mbytes[s]);
  cnt += __shfl_xor(cnt, 16);
  cnt += __shfl_xor(cnt, 32);
  const float inv = (cnt > 0) ? (1.0f / (float)cnt) : 0.0f;

  const uint4* sbl = &sB[lane];
  f32x4 acc[4];
#pragma unroll
  for (int nt = 0; nt < 4; ++nt) acc[nt] = (f32x4){0.f, 0.f, 0.f, 0.f};

  uint4 bc[4], bn[4];
#pragma unroll
  for (int nt = 0; nt < 4; ++nt) bc[nt] = sbl[nt * 64];

#pragma unroll
  for (int s = 0; s < 16; ++s) {
    if (s + 1 < 16) {
#pragma unroll
      for (int nt = 0; nt < 4; ++nt) bn[nt] = sbl[((s + 1) * 4 + nt) * 64];
    }
    const uint32_t byte = mbytes[s];
    bf16x8 af;
#pragma unroll
    for (int e = 0; e < 8; ++e) af[e] = ((byte >> e) & 1u) ? (short)0x3F80 : (short)0;

#pragma unroll
    for (int nt = 0; nt < 4; ++nt)
      acc[nt] = __builtin_amdgcn_mfma_f32_16x16x32_bf16(
          af, *reinterpret_cast<const bf16x8*>(&bc[nt]), acc[nt], 0, 0, 0);

#pragma unroll
    for (int nt = 0; nt < 4; ++nt) bc[nt] = bn[nt];
  }

  // ---- epilogue: C/D layout col = lane&15, row = kq*4 + reg ----
#pragma unroll
  for (int r = 0; r < 4; ++r) {
    const int row = kq * 4 + r;
    const float invr = __shfl(inv, row);   // lane 'row' holds that row's count
    float* orow = out + (size_t)(t0 + row) * D_DIM + m;
#pragma unroll
    for (int nt = 0; nt < 4; ++nt)
      orow[16 * nt] = acc[nt][r] * invr;
  }
}

extern "C" void kernel_launch(void* const* d_in, const int* in_sizes, int n_in,
                              void* d_out, int out_size, void* d_ws, size_t ws_size,
                              hipStream_t stream) {
  const float* flags = (const float*)d_in[0];
  const float* W     = (const float*)d_in[1];
  float* out         = (float*)d_out;

  const int blocks = (TILES + 7) / 8;   // 782: 8 waves/block, one 16-row tile per wave
  hipLaunchKernelGGL(flagbag_kernel, dim3(blocks), dim3(512), 0, stream, flags, W, out);
}